// Round 13
// baseline (115.137 us; speedup 1.0000x reference)
//
#include <hip/hip_runtime.h>

typedef __fp16 f16;
typedef __attribute__((ext_vector_type(4))) __fp16 h16x4;
typedef __attribute__((ext_vector_type(4))) float f32x4;

#define NLOG2E  (-1.4426950408889634f)   // -log2(e): i,f,o gate scale
#define P2LOG2E ( 2.8853900817779268f)   // +2*log2(e): g gate scale / cs mul

__device__ __forceinline__ float tanh_fast(float x) {
    // epilogue-only helper
    return 1.0f - 2.0f * __builtin_amdgcn_rcpf(1.0f + __expf(2.0f * x));
}
__device__ __forceinline__ h16x4 cvt4(float4 v) {
    h16x4 r; r[0] = (f16)v.x; r[1] = (f16)v.y; r[2] = (f16)v.z; r[3] = (f16)v.w;
    return r;
}
__device__ __forceinline__ h16x4 cvt4s(float4 v, float s) {
    h16x4 r; r[0] = (f16)(v.x * s); r[1] = (f16)(v.y * s);
    r[2] = (f16)(v.z * s); r[3] = (f16)(v.w * s);
    return r;
}
__device__ __forceinline__ h16x4 pack4(float a, float b, float c, float d) {
    auto p0 = __builtin_amdgcn_cvt_pkrtz(a, b);
    auto p1 = __builtin_amdgcn_cvt_pkrtz(c, d);
    uint2 u = make_uint2(__builtin_bit_cast(unsigned, p0),
                         __builtin_bit_cast(unsigned, p1));
    return __builtin_bit_cast(h16x4, u);
}
__device__ __forceinline__ float sel4(f32x4 v, bool q1, bool q2) {
    float a = q1 ? v[1] : v[0];
    float b = q1 ? v[3] : v[2];
    return q2 ? b : a;
}

// R13 = R8 skeleton + per-gate log2e folding: gate rows (Wih, Whh, biases)
// pre-scaled by -log2e (i,f,o) / +2log2e (g) so activations use exp2
// directly (v_exp_f32 IS 2^x) — removes the 5 per-step v_mul-by-log2e,
// 2 of them on the serial chain. Everything else byte-identical to R8/R12.
__global__ __launch_bounds__(128) void reflex_fused(
    const float* __restrict__ x,
    const float* __restrict__ h0, const float* __restrict__ c0,
    const float* __restrict__ W1, const float* __restrict__ b1,
    const float* __restrict__ Wih, const float* __restrict__ Whh,
    const float* __restrict__ bih, const float* __restrict__ bhh,
    const float* __restrict__ W2, const float* __restrict__ b2,
    float* __restrict__ dout)
{
    const int tid = threadIdx.x;
    const int lane = tid & 63;
    const int m = lane & 15, hi = lane >> 4;
    const int b0 = blockIdx.x << 2;

    // [2 buf][16 t][4 G][4 hi][4 e] f32x4 C-fragments = 32 KB
    __shared__ f32x4 xgl[2][1024];

    // per-gate scale: i,f,o -> -log2e ; g -> +2log2e
    const float gsc0 = NLOG2E, gsc1 = NLOG2E, gsc2 = P2LOG2E, gsc3 = NLOG2E;

    if (tid >= 64) {
        // ---------------- producer wave ----------------
        const int e = m & 3, q = m >> 2;
        const int b = b0 + e;
        h16x4 a1[2]; f32x4 c1[2];
#pragma unroll
        for (int nt = 0; nt < 2; ++nt) {
            float4 wv = make_float4(0.f, 0.f, 0.f, 0.f);
            if (hi < 3) wv = *(const float4*)(W1 + (nt * 16 + m) * 12 + 4 * hi);
            a1[nt] = cvt4(wv);
            float4 bv = *(const float4*)(b1 + nt * 16 + 4 * hi);
            c1[nt] = f32x4{bv.x, bv.y, bv.z, bv.w};
        }
        h16x4 a2[4][2]; f32x4 cbp[4];
        const float gscv[4] = {gsc0, gsc1, gsc2, gsc3};
#pragma unroll
        for (int G = 0; G < 4; ++G) {
            const int gr = G * 16 + m;
            const float s = gscv[G];
#pragma unroll
            for (int s_ = 0; s_ < 2; ++s_)
                a2[G][s_] = cvt4s(*(const float4*)(Wih + gr * 32 + s_ * 16 + 4 * hi), s);
            float4 bi = *(const float4*)(bih + G * 16 + 4 * hi);
            float4 bh = *(const float4*)(bhh + G * 16 + 4 * hi);
            cbp[G] = f32x4{(bi.x + bh.x) * s, (bi.y + bh.y) * s,
                           (bi.z + bh.z) * s, (bi.w + bh.w) * s};
        }
        f32x4* pst0 = &xgl[0][q * 64 + hi * 4 + e];
        f32x4* pst1 = &xgl[1][q * 64 + hi * 4 + e];
        const float* xp = x + ((size_t)b * 512 + q) * 12 + 4 * hi;
        float4 BXA[4], BXB[4];

#define LOADT(BX) do {                                                         \
    if (hi < 3) {                                                              \
        BX[0] = *(const float4*)(xp);                                          \
        BX[1] = *(const float4*)(xp + 48);                                     \
        BX[2] = *(const float4*)(xp + 96);                                     \
        BX[3] = *(const float4*)(xp + 144);                                    \
    }                                                                          \
    xp += 192;                                                                 \
} while (0)

#define GENSLICE(PST, BXV, CC) do {                                            \
    h16x4 bx = {0, 0, 0, 0};                                                   \
    if (hi < 3) bx = cvt4(BXV);                                                \
    f32x4 d0 = __builtin_amdgcn_mfma_f32_16x16x16f16(a1[0], bx, c1[0],0,0,0);  \
    f32x4 d1 = __builtin_amdgcn_mfma_f32_16x16x16f16(a1[1], bx, c1[1],0,0,0);  \
    h16x4 u0 = pack4(fmaxf(d0[0],0.f), fmaxf(d0[1],0.f),                       \
                     fmaxf(d0[2],0.f), fmaxf(d0[3],0.f));                      \
    h16x4 u1 = pack4(fmaxf(d1[0],0.f), fmaxf(d1[1],0.f),                       \
                     fmaxf(d1[2],0.f), fmaxf(d1[3],0.f));                      \
    f32x4 A0 = __builtin_amdgcn_mfma_f32_16x16x16f16(a2[0][0], u0, cbp[0],0,0,0);\
    f32x4 A1 = __builtin_amdgcn_mfma_f32_16x16x16f16(a2[1][0], u0, cbp[1],0,0,0);\
    f32x4 A2 = __builtin_amdgcn_mfma_f32_16x16x16f16(a2[2][0], u0, cbp[2],0,0,0);\
    f32x4 A3 = __builtin_amdgcn_mfma_f32_16x16x16f16(a2[3][0], u0, cbp[3],0,0,0);\
    A0 = __builtin_amdgcn_mfma_f32_16x16x16f16(a2[0][1], u1, A0, 0, 0, 0);     \
    A1 = __builtin_amdgcn_mfma_f32_16x16x16f16(a2[1][1], u1, A1, 0, 0, 0);     \
    A2 = __builtin_amdgcn_mfma_f32_16x16x16f16(a2[2][1], u1, A2, 0, 0, 0);     \
    A3 = __builtin_amdgcn_mfma_f32_16x16x16f16(a2[3][1], u1, A3, 0, 0, 0);     \
    (PST)[(CC) * 256 +  0] = A0;                                               \
    (PST)[(CC) * 256 + 16] = A1;                                               \
    (PST)[(CC) * 256 + 32] = A2;                                               \
    (PST)[(CC) * 256 + 48] = A3;                                               \
} while (0)

#define GENT(PST, BX) do {                                                     \
    GENSLICE(PST, BX[0], 0); GENSLICE(PST, BX[1], 1);                          \
    GENSLICE(PST, BX[2], 2); GENSLICE(PST, BX[3], 3);                          \
} while (0)

        LOADT(BXA);                       // tile 0
        for (int F2 = 0; F2 < 16; ++F2) {
            LOADT(BXB);                   // tile 2*F2+1
            GENT(pst0, BXA);              // tile 2*F2 -> buf0
            __syncthreads();
            if (F2 < 15) LOADT(BXA);      // tile 2*F2+2
            GENT(pst1, BXB);              // tile 2*F2+1 -> buf1
            __syncthreads();
        }
#undef LOADT
#undef GENSLICE
#undef GENT
    } else {
        // ---------------- consumer wave ----------------
        const int e = m >> 2, q = m & 3;
        const int b = b0 + e;
        const bool q1 = (q & 1) != 0, q2 = (q & 2) != 0;

        h16x4 ar[4];
        const float gscv[4] = {gsc0, gsc1, gsc2, gsc3};
#pragma unroll
        for (int G = 0; G < 4; ++G)
            ar[G] = cvt4s(*(const float4*)(Whh + (G * 16 + m) * 16 + 4 * hi),
                          gscv[G]);
        h16x4 hf = cvt4(*(const float4*)(h0 + b * 16 + 4 * hi));
        float cs = c0[b * 16 + 4 * hi + q];
        float hn = 0.f;
        const f32x4* ldsr = &xgl[0][0];
        const int vbi = hi * 4 + e;

        // gates arrive pre-scaled: i,f,o by -log2e ; g by +2log2e.
        // sigm(x) = rcp(1+exp2(x_s)); tanh(g) = 1-2*rcp(1+exp2(g_s)).
#define STEP(TT, CF, OFF) do {                                                 \
    f32x4 dg = __builtin_amdgcn_mfma_f32_16x16x16f16(ar[2], hf, CF[2],0,0,0);  \
    f32x4 df = __builtin_amdgcn_mfma_f32_16x16x16f16(ar[1], hf, CF[1],0,0,0);  \
    f32x4 di = __builtin_amdgcn_mfma_f32_16x16x16f16(ar[0], hf, CF[0],0,0,0);  \
    f32x4 dq = __builtin_amdgcn_mfma_f32_16x16x16f16(ar[3], hf, CF[3],0,0,0);  \
    if ((TT) < 14) {                                                           \
        CF[0] = ldsr[(OFF) + ((TT) + 2) * 64 +  0 + vbi];                      \
        CF[1] = ldsr[(OFF) + ((TT) + 2) * 64 + 16 + vbi];                      \
        CF[2] = ldsr[(OFF) + ((TT) + 2) * 64 + 32 + vbi];                      \
        CF[3] = ldsr[(OFF) + ((TT) + 2) * 64 + 48 + vbi];                      \
    }                                                                          \
    float gg = sel4(dg, q1, q2); float gf = sel4(df, q1, q2);                  \
    float gi = sel4(di, q1, q2); float go = sel4(dq, q1, q2);                  \
    float tg = 1.0f - 2.0f * __builtin_amdgcn_rcpf(1.0f + exp2f(gg));          \
    float si = __builtin_amdgcn_rcpf(1.0f + exp2f(gi));                        \
    float sf = __builtin_amdgcn_rcpf(1.0f + exp2f(gf));                        \
    cs = fmaf(sf, cs, si * tg);                                                \
    float so = __builtin_amdgcn_rcpf(1.0f + exp2f(go));                        \
    float ts = 1.0f - 2.0f * __builtin_amdgcn_rcpf(                            \
                   1.0f + exp2f(cs * P2LOG2E));                                \
    hn = so * ts;                                                              \
    int hnb = __builtin_bit_cast(int, hn);                                     \
    float j0 = __builtin_bit_cast(float,                                       \
        __builtin_amdgcn_mov_dpp(hnb, 0x00, 0xF, 0xF, true));                  \
    float j1 = __builtin_bit_cast(float,                                       \
        __builtin_amdgcn_mov_dpp(hnb, 0x55, 0xF, 0xF, true));                  \
    float j2 = __builtin_bit_cast(float,                                       \
        __builtin_amdgcn_mov_dpp(hnb, 0xAA, 0xF, 0xF, true));                  \
    float j3 = __builtin_bit_cast(float,                                       \
        __builtin_amdgcn_mov_dpp(hnb, 0xFF, 0xF, 0xF, true));                  \
    hf = pack4(j0, j1, j2, j3);                                                \
} while (0)

#define TILEBODY(OFF) do {                                                     \
    f32x4 CA[4], CB[4];                                                        \
    CA[0] = ldsr[(OFF) +  0 + vbi]; CA[1] = ldsr[(OFF) + 16 + vbi];            \
    CA[2] = ldsr[(OFF) + 32 + vbi]; CA[3] = ldsr[(OFF) + 48 + vbi];            \
    CB[0] = ldsr[(OFF) + 64 + vbi]; CB[1] = ldsr[(OFF) + 80 + vbi];            \
    CB[2] = ldsr[(OFF) + 96 + vbi]; CB[3] = ldsr[(OFF) + 112 + vbi];           \
    STEP(0, CA, OFF);  STEP(1, CB, OFF);                                       \
    STEP(2, CA, OFF);  STEP(3, CB, OFF);                                       \
    STEP(4, CA, OFF);  STEP(5, CB, OFF);                                       \
    STEP(6, CA, OFF);  STEP(7, CB, OFF);                                       \
    STEP(8, CA, OFF);  STEP(9, CB, OFF);                                       \
    STEP(10, CA, OFF); STEP(11, CB, OFF);                                      \
    STEP(12, CA, OFF); STEP(13, CB, OFF);                                      \
    STEP(14, CA, OFF); STEP(15, CB, OFF);                                      \
} while (0)

        __builtin_amdgcn_s_setprio(1);
        for (int T2 = 0; T2 < 16; ++T2) {
            __syncthreads();
            TILEBODY(0);
            __syncthreads();
            TILEBODY(1024);
        }
        __builtin_amdgcn_s_setprio(0);
#undef STEP
#undef TILEBODY

        // ---- outputs ----
        dout[4096 + b * 16 + 4 * hi + q]         = hn;   // hT [1,B,H]
        dout[4096 + 65536 + b * 16 + 4 * hi + q] = cs;   // cT [1,B,H]
        float p = hn * W2[4 * hi + q];
        p += __shfl_xor(p, 1);
        p += __shfl_xor(p, 2);
        p += __shfl_xor(p, 16);
        p += __shfl_xor(p, 32);
        if (hi == 0 && q == 0) dout[b0 + e] = tanh_fast(p + b2[0]);  // out [B,1]
    }
}

extern "C" void kernel_launch(void* const* d_in, const int* in_sizes, int n_in,
                              void* d_out, int out_size, void* d_ws, size_t ws_size,
                              hipStream_t stream)
{
    const float* x   = (const float*)d_in[0];
    const float* h0  = (const float*)d_in[1];
    const float* c0  = (const float*)d_in[2];
    const float* W1  = (const float*)d_in[3];
    const float* b1  = (const float*)d_in[4];
    const float* Wih = (const float*)d_in[5];
    const float* Whh = (const float*)d_in[6];
    const float* bih = (const float*)d_in[7];
    const float* bhh = (const float*)d_in[8];
    const float* W2  = (const float*)d_in[9];
    const float* b2  = (const float*)d_in[10];
    float* out = (float*)d_out;

    reflex_fused<<<dim3(1024), dim3(128), 0, stream>>>(
        x, h0, c0, W1, b1, Wih, Whh, bih, bhh, W2, b2, out);
}

// Round 14
// 92.335 us; speedup vs baseline: 1.2469x; 1.2469x over previous
//
#include <hip/hip_runtime.h>

typedef __fp16 f16;
typedef __attribute__((ext_vector_type(4))) __fp16 h16x4;
typedef __attribute__((ext_vector_type(4))) float f32x4;

#define NLOG2E  (-1.4426950408889634f)   // -log2(e): i,f,o gate scale
#define P2LOG2E ( 2.8853900817779268f)   // +2*log2(e): g gate scale / cs mul

__device__ __forceinline__ float tanh_fast(float x) {
    // epilogue-only helper
    return 1.0f - 2.0f * __builtin_amdgcn_rcpf(1.0f + __expf(2.0f * x));
}
__device__ __forceinline__ h16x4 cvt4(float4 v) {
    h16x4 r; r[0] = (f16)v.x; r[1] = (f16)v.y; r[2] = (f16)v.z; r[3] = (f16)v.w;
    return r;
}
__device__ __forceinline__ h16x4 cvt4s(float4 v, float s) {
    h16x4 r; r[0] = (f16)(v.x * s); r[1] = (f16)(v.y * s);
    r[2] = (f16)(v.z * s); r[3] = (f16)(v.w * s);
    return r;
}
__device__ __forceinline__ h16x4 pack4(float a, float b, float c, float d) {
    auto p0 = __builtin_amdgcn_cvt_pkrtz(a, b);
    auto p1 = __builtin_amdgcn_cvt_pkrtz(c, d);
    uint2 u = make_uint2(__builtin_bit_cast(unsigned, p0),
                         __builtin_bit_cast(unsigned, p1));
    return __builtin_bit_cast(h16x4, u);
}
__device__ __forceinline__ float sel4(f32x4 v, bool q1, bool q2) {
    float a = q1 ? v[1] : v[0];
    float b = q1 ? v[3] : v[2];
    return q2 ? b : a;
}

// R14 = R13's log2e-folding with the CORRECT exp2: __builtin_amdgcn_exp2f
// (raw v_exp_f32, 1 instr) instead of libm exp2f (precise path with fixup
// code — that was R13's regression). Gate rows pre-scaled by -log2e
// (i,f,o) / +2log2e (g); activations are rcp(1+v_exp(y)) directly.
// Skeleton byte-identical to R8/R12.
__global__ __launch_bounds__(128) void reflex_fused(
    const float* __restrict__ x,
    const float* __restrict__ h0, const float* __restrict__ c0,
    const float* __restrict__ W1, const float* __restrict__ b1,
    const float* __restrict__ Wih, const float* __restrict__ Whh,
    const float* __restrict__ bih, const float* __restrict__ bhh,
    const float* __restrict__ W2, const float* __restrict__ b2,
    float* __restrict__ dout)
{
    const int tid = threadIdx.x;
    const int lane = tid & 63;
    const int m = lane & 15, hi = lane >> 4;
    const int b0 = blockIdx.x << 2;

    // [2 buf][16 t][4 G][4 hi][4 e] f32x4 C-fragments = 32 KB
    __shared__ f32x4 xgl[2][1024];

    // per-gate scale: i,f,o -> -log2e ; g -> +2log2e
    const float gscv[4] = {NLOG2E, NLOG2E, P2LOG2E, NLOG2E};

    if (tid >= 64) {
        // ---------------- producer wave ----------------
        const int e = m & 3, q = m >> 2;
        const int b = b0 + e;
        h16x4 a1[2]; f32x4 c1[2];
#pragma unroll
        for (int nt = 0; nt < 2; ++nt) {
            float4 wv = make_float4(0.f, 0.f, 0.f, 0.f);
            if (hi < 3) wv = *(const float4*)(W1 + (nt * 16 + m) * 12 + 4 * hi);
            a1[nt] = cvt4(wv);
            float4 bv = *(const float4*)(b1 + nt * 16 + 4 * hi);
            c1[nt] = f32x4{bv.x, bv.y, bv.z, bv.w};
        }
        h16x4 a2[4][2]; f32x4 cbp[4];
#pragma unroll
        for (int G = 0; G < 4; ++G) {
            const int gr = G * 16 + m;
            const float s = gscv[G];
#pragma unroll
            for (int s_ = 0; s_ < 2; ++s_)
                a2[G][s_] = cvt4s(*(const float4*)(Wih + gr * 32 + s_ * 16 + 4 * hi), s);
            float4 bi = *(const float4*)(bih + G * 16 + 4 * hi);
            float4 bh = *(const float4*)(bhh + G * 16 + 4 * hi);
            cbp[G] = f32x4{(bi.x + bh.x) * s, (bi.y + bh.y) * s,
                           (bi.z + bh.z) * s, (bi.w + bh.w) * s};
        }
        f32x4* pst0 = &xgl[0][q * 64 + hi * 4 + e];
        f32x4* pst1 = &xgl[1][q * 64 + hi * 4 + e];
        const float* xp = x + ((size_t)b * 512 + q) * 12 + 4 * hi;
        float4 BXA[4], BXB[4];

#define LOADT(BX) do {                                                         \
    if (hi < 3) {                                                              \
        BX[0] = *(const float4*)(xp);                                          \
        BX[1] = *(const float4*)(xp + 48);                                     \
        BX[2] = *(const float4*)(xp + 96);                                     \
        BX[3] = *(const float4*)(xp + 144);                                    \
    }                                                                          \
    xp += 192;                                                                 \
} while (0)

#define GENSLICE(PST, BXV, CC) do {                                            \
    h16x4 bx = {0, 0, 0, 0};                                                   \
    if (hi < 3) bx = cvt4(BXV);                                                \
    f32x4 d0 = __builtin_amdgcn_mfma_f32_16x16x16f16(a1[0], bx, c1[0],0,0,0);  \
    f32x4 d1 = __builtin_amdgcn_mfma_f32_16x16x16f16(a1[1], bx, c1[1],0,0,0);  \
    h16x4 u0 = pack4(fmaxf(d0[0],0.f), fmaxf(d0[1],0.f),                       \
                     fmaxf(d0[2],0.f), fmaxf(d0[3],0.f));                      \
    h16x4 u1 = pack4(fmaxf(d1[0],0.f), fmaxf(d1[1],0.f),                       \
                     fmaxf(d1[2],0.f), fmaxf(d1[3],0.f));                      \
    f32x4 A0 = __builtin_amdgcn_mfma_f32_16x16x16f16(a2[0][0], u0, cbp[0],0,0,0);\
    f32x4 A1 = __builtin_amdgcn_mfma_f32_16x16x16f16(a2[1][0], u0, cbp[1],0,0,0);\
    f32x4 A2 = __builtin_amdgcn_mfma_f32_16x16x16f16(a2[2][0], u0, cbp[2],0,0,0);\
    f32x4 A3 = __builtin_amdgcn_mfma_f32_16x16x16f16(a2[3][0], u0, cbp[3],0,0,0);\
    A0 = __builtin_amdgcn_mfma_f32_16x16x16f16(a2[0][1], u1, A0, 0, 0, 0);     \
    A1 = __builtin_amdgcn_mfma_f32_16x16x16f16(a2[1][1], u1, A1, 0, 0, 0);     \
    A2 = __builtin_amdgcn_mfma_f32_16x16x16f16(a2[2][1], u1, A2, 0, 0, 0);     \
    A3 = __builtin_amdgcn_mfma_f32_16x16x16f16(a2[3][1], u1, A3, 0, 0, 0);     \
    (PST)[(CC) * 256 +  0] = A0;                                               \
    (PST)[(CC) * 256 + 16] = A1;                                               \
    (PST)[(CC) * 256 + 32] = A2;                                               \
    (PST)[(CC) * 256 + 48] = A3;                                               \
} while (0)

#define GENT(PST, BX) do {                                                     \
    GENSLICE(PST, BX[0], 0); GENSLICE(PST, BX[1], 1);                          \
    GENSLICE(PST, BX[2], 2); GENSLICE(PST, BX[3], 3);                          \
} while (0)

        LOADT(BXA);                       // tile 0
        for (int F2 = 0; F2 < 16; ++F2) {
            LOADT(BXB);                   // tile 2*F2+1
            GENT(pst0, BXA);              // tile 2*F2 -> buf0
            __syncthreads();
            if (F2 < 15) LOADT(BXA);      // tile 2*F2+2
            GENT(pst1, BXB);              // tile 2*F2+1 -> buf1
            __syncthreads();
        }
#undef LOADT
#undef GENSLICE
#undef GENT
    } else {
        // ---------------- consumer wave ----------------
        const int e = m >> 2, q = m & 3;
        const int b = b0 + e;
        const bool q1 = (q & 1) != 0, q2 = (q & 2) != 0;

        h16x4 ar[4];
#pragma unroll
        for (int G = 0; G < 4; ++G)
            ar[G] = cvt4s(*(const float4*)(Whh + (G * 16 + m) * 16 + 4 * hi),
                          gscv[G]);
        h16x4 hf = cvt4(*(const float4*)(h0 + b * 16 + 4 * hi));
        float cs = c0[b * 16 + 4 * hi + q];
        float hn = 0.f;
        const f32x4* ldsr = &xgl[0][0];
        const int vbi = hi * 4 + e;

        // gates pre-scaled: sigm = rcp(1+v_exp(y)); tanh_g = 1-2*rcp(1+v_exp(y)).
#define STEP(TT, CF, OFF) do {                                                 \
    f32x4 dg = __builtin_amdgcn_mfma_f32_16x16x16f16(ar[2], hf, CF[2],0,0,0);  \
    f32x4 df = __builtin_amdgcn_mfma_f32_16x16x16f16(ar[1], hf, CF[1],0,0,0);  \
    f32x4 di = __builtin_amdgcn_mfma_f32_16x16x16f16(ar[0], hf, CF[0],0,0,0);  \
    f32x4 dq = __builtin_amdgcn_mfma_f32_16x16x16f16(ar[3], hf, CF[3],0,0,0);  \
    if ((TT) < 14) {                                                           \
        CF[0] = ldsr[(OFF) + ((TT) + 2) * 64 +  0 + vbi];                      \
        CF[1] = ldsr[(OFF) + ((TT) + 2) * 64 + 16 + vbi];                      \
        CF[2] = ldsr[(OFF) + ((TT) + 2) * 64 + 32 + vbi];                      \
        CF[3] = ldsr[(OFF) + ((TT) + 2) * 64 + 48 + vbi];                      \
    }                                                                          \
    float gg = sel4(dg, q1, q2); float gf = sel4(df, q1, q2);                  \
    float gi = sel4(di, q1, q2); float go = sel4(dq, q1, q2);                  \
    float tg = 1.0f - 2.0f * __builtin_amdgcn_rcpf(                            \
                   1.0f + __builtin_amdgcn_exp2f(gg));                         \
    float si = __builtin_amdgcn_rcpf(1.0f + __builtin_amdgcn_exp2f(gi));       \
    float sf = __builtin_amdgcn_rcpf(1.0f + __builtin_amdgcn_exp2f(gf));       \
    cs = fmaf(sf, cs, si * tg);                                                \
    float so = __builtin_amdgcn_rcpf(1.0f + __builtin_amdgcn_exp2f(go));       \
    float ts = 1.0f - 2.0f * __builtin_amdgcn_rcpf(                            \
                   1.0f + __builtin_amdgcn_exp2f(cs * P2LOG2E));               \
    hn = so * ts;                                                              \
    int hnb = __builtin_bit_cast(int, hn);                                     \
    float j0 = __builtin_bit_cast(float,                                       \
        __builtin_amdgcn_mov_dpp(hnb, 0x00, 0xF, 0xF, true));                  \
    float j1 = __builtin_bit_cast(float,                                       \
        __builtin_amdgcn_mov_dpp(hnb, 0x55, 0xF, 0xF, true));                  \
    float j2 = __builtin_bit_cast(float,                                       \
        __builtin_amdgcn_mov_dpp(hnb, 0xAA, 0xF, 0xF, true));                  \
    float j3 = __builtin_bit_cast(float,                                       \
        __builtin_amdgcn_mov_dpp(hnb, 0xFF, 0xF, 0xF, true));                  \
    hf = pack4(j0, j1, j2, j3);                                                \
} while (0)

#define TILEBODY(OFF) do {                                                     \
    f32x4 CA[4], CB[4];                                                        \
    CA[0] = ldsr[(OFF) +  0 + vbi]; CA[1] = ldsr[(OFF) + 16 + vbi];            \
    CA[2] = ldsr[(OFF) + 32 + vbi]; CA[3] = ldsr[(OFF) + 48 + vbi];            \
    CB[0] = ldsr[(OFF) + 64 + vbi]; CB[1] = ldsr[(OFF) + 80 + vbi];            \
    CB[2] = ldsr[(OFF) + 96 + vbi]; CB[3] = ldsr[(OFF) + 112 + vbi];           \
    STEP(0, CA, OFF);  STEP(1, CB, OFF);                                       \
    STEP(2, CA, OFF);  STEP(3, CB, OFF);                                       \
    STEP(4, CA, OFF);  STEP(5, CB, OFF);                                       \
    STEP(6, CA, OFF);  STEP(7, CB, OFF);                                       \
    STEP(8, CA, OFF);  STEP(9, CB, OFF);                                       \
    STEP(10, CA, OFF); STEP(11, CB, OFF);                                      \
    STEP(12, CA, OFF); STEP(13, CB, OFF);                                      \
    STEP(14, CA, OFF); STEP(15, CB, OFF);                                      \
} while (0)

        __builtin_amdgcn_s_setprio(1);
        for (int T2 = 0; T2 < 16; ++T2) {
            __syncthreads();
            TILEBODY(0);
            __syncthreads();
            TILEBODY(1024);
        }
        __builtin_amdgcn_s_setprio(0);
#undef STEP
#undef TILEBODY

        // ---- outputs ----
        dout[4096 + b * 16 + 4 * hi + q]         = hn;   // hT [1,B,H]
        dout[4096 + 65536 + b * 16 + 4 * hi + q] = cs;   // cT [1,B,H]
        float p = hn * W2[4 * hi + q];
        p += __shfl_xor(p, 1);
        p += __shfl_xor(p, 2);
        p += __shfl_xor(p, 16);
        p += __shfl_xor(p, 32);
        if (hi == 0 && q == 0) dout[b0 + e] = tanh_fast(p + b2[0]);  // out [B,1]
    }
}

extern "C" void kernel_launch(void* const* d_in, const int* in_sizes, int n_in,
                              void* d_out, int out_size, void* d_ws, size_t ws_size,
                              hipStream_t stream)
{
    const float* x   = (const float*)d_in[0];
    const float* h0  = (const float*)d_in[1];
    const float* c0  = (const float*)d_in[2];
    const float* W1  = (const float*)d_in[3];
    const float* b1  = (const float*)d_in[4];
    const float* Wih = (const float*)d_in[5];
    const float* Whh = (const float*)d_in[6];
    const float* bih = (const float*)d_in[7];
    const float* bhh = (const float*)d_in[8];
    const float* W2  = (const float*)d_in[9];
    const float* b2  = (const float*)d_in[10];
    float* out = (float*)d_out;

    reflex_fused<<<dim3(1024), dim3(128), 0, stream>>>(
        x, h0, c0, W1, b1, Wih, Whh, bih, bhh, W2, b2, out);
}